// Round 12
// baseline (30.003 us; speedup 1.0000x reference)
//
#include <hip/hip_runtime.h>

namespace {

constexpr int EMB  = 64;
constexpr int NCLS = 64;
constexpr int BTOT = 4096;
constexpr int S4   = 17;   // float4 stride for fallback LDS tiles

typedef __bf16 bf16x8 __attribute__((ext_vector_type(8)));
typedef float  f32x4  __attribute__((ext_vector_type(4)));

// ---------------- ws layout ----------------
constexpr size_t KS_OFF   = 0;                                  // 4096*64 f32 = 1 MB
constexpr size_t PART_OFF = (size_t)BTOT * NCLS * 4;            // 64 f32 partials
constexpr size_t CNT_OFF  = PART_OFF + 64 * 4;                  // 1 int counter
constexpr size_t WS_NEED  = CNT_OFF + 16;

// Load 16 floats of one row (k = koff..+8 and koff+32..+8), convert to two
// bf16x8 fragments, return this lane's partial squared-norm contribution.
// Validated numerics: rounds 4/5 (absmax 0 in R5).
__device__ __forceinline__ float cvt16(const float* __restrict__ p,
                                       bf16x8& lo, bf16x8& hi) {
  const float4 f0 = *(const float4*)(p);
  const float4 f1 = *(const float4*)(p + 4);
  const float4 f2 = *(const float4*)(p + 32);
  const float4 f3 = *(const float4*)(p + 36);
  lo[0] = (__bf16)f0.x; lo[1] = (__bf16)f0.y; lo[2] = (__bf16)f0.z; lo[3] = (__bf16)f0.w;
  lo[4] = (__bf16)f1.x; lo[5] = (__bf16)f1.y; lo[6] = (__bf16)f1.z; lo[7] = (__bf16)f1.w;
  hi[0] = (__bf16)f2.x; hi[1] = (__bf16)f2.y; hi[2] = (__bf16)f2.z; hi[3] = (__bf16)f2.w;
  hi[4] = (__bf16)f3.x; hi[5] = (__bf16)f3.y; hi[6] = (__bf16)f3.z; hi[7] = (__bf16)f3.w;
  float s = f0.x * f0.x + f0.y * f0.y + f0.z * f0.z + f0.w * f0.w;
  s = fmaf(f1.x, f1.x, s); s = fmaf(f1.y, f1.y, s); s = fmaf(f1.z, f1.z, s); s = fmaf(f1.w, f1.w, s);
  s = fmaf(f2.x, f2.x, s); s = fmaf(f2.y, f2.y, s); s = fmaf(f2.z, f2.z, s); s = fmaf(f2.w, f2.w, s);
  s = fmaf(f3.x, f3.x, s); s = fmaf(f3.y, f3.y, s); s = fmaf(f3.z, f3.z, s); s = fmaf(f3.w, f3.w, s);
  return s;
}

// ---------------- kernel 1: Ksum via MFMA (fat structure, inline cvt) ----------------
// grid 1024 x 256: block -> (rg = bid>>4: 64 rows, cg = bid&15), wave w -> class cg*4+w.
// Wave: 4 row-tiles x 4 col-tiles, 2 MFMA (K=64) each. fp32 emb read directly;
// bf16 conversion + squared norms computed in-register (shfl_xor 16/32 reduce).
// Fast sqrt (v_sqrt_f32 raw) + exp2 with folded log2(e). No fences; block 0
// resets the loss kernel's counter (visible across the kernel boundary).
__global__ __launch_bounds__(256, 4) void kde_ksum_mfma(const float* __restrict__ emb,
                                                        const float* __restrict__ bwv,
                                                        float* __restrict__ ksum,
                                                        int* __restrict__ cnt) {
  const int tid  = threadIdx.x;
  const int wave = tid >> 6;
  const int lane = tid & 63;
  const int bid  = blockIdx.x;
  const int rowBase = (bid >> 4) * 64;
  const int cls  = (bid & 15) * 4 + wave;
  const int colBase = cls * 64;

  if (bid == 0 && tid == 0) *cnt = 0;   // for kde_loss3 (later dispatch)

  const int lr = lane & 15;   // A row / B col within 16
  const int kg = lane >> 4;   // k-group (16 of 64 elems per lane)
  const int koff = kg * 8;

  // A fragments: 4 row-tiles, converted in-register; row norms via shfl
  bf16x8 a0[4], a1[4];
  float sqr[4];
#pragma unroll
  for (int rt = 0; rt < 4; ++rt) {
    float s = cvt16(emb + (rowBase + rt * 16 + lr) * EMB + koff, a0[rt], a1[rt]);
    s += __shfl_xor(s, 16);
    s += __shfl_xor(s, 32);
    sqr[rt] = s;                       // ||row rowBase + rt*16 + lr||^2
  }
  // norms for this lane's D rows (rt*16 + kg*4 + i): broadcast from lane kg*4+i
  float srv[16];
#pragma unroll
  for (int rt = 0; rt < 4; ++rt)
#pragma unroll
    for (int i = 0; i < 4; ++i)
      srv[rt * 4 + i] = __shfl(sqr[rt], kg * 4 + i);

  constexpr float NLOG2E = -1.4426950408889634f;   // -log2(e)
  const float nl2bw = NLOG2E / (2.0f * bwv[cls]);

  float ksr[16];
#pragma unroll
  for (int v = 0; v < 16; ++v) ksr[v] = 0.f;

#pragma unroll
  for (int ct = 0; ct < 4; ++ct) {
    const int c0 = colBase + ct * 16;
    bf16x8 b0, b1;
    float sc = cvt16(emb + (c0 + lr) * EMB + koff, b0, b1);
    sc += __shfl_xor(sc, 16);
    sc += __shfl_xor(sc, 32);          // ||col c0+lr||^2
    const int gc = c0 + lr;
#pragma unroll
    for (int rt = 0; rt < 4; ++rt) {
      f32x4 acc = {0.f, 0.f, 0.f, 0.f};
      acc = __builtin_amdgcn_mfma_f32_16x16x32_bf16(a0[rt], b0, acc, 0, 0, 0);
      acc = __builtin_amdgcn_mfma_f32_16x16x32_bf16(a1[rt], b1, acc, 0, 0, 0);
      // D layout: col = lane&15 (= gc), row = kg*4 + i
#pragma unroll
      for (int i = 0; i < 4; ++i) {
        const int gr = rowBase + rt * 16 + kg * 4 + i;
        float d2 = fmaf(-2.f, acc[i], srv[rt * 4 + i] + sc);
        d2 = fmaxf(d2, 0.f);
        const float dist = __builtin_amdgcn_sqrtf(d2);   // raw v_sqrt_f32
        const float Kv = exp2f(dist * nl2bw);            // exp(-dist/(2bw))
        ksr[rt * 4 + i] += (gr != gc) ? Kv : 0.f;
      }
    }
  }

  // reduce over the 16 lanes (lr) that hold different cols
#pragma unroll
  for (int m = 1; m < 16; m <<= 1) {
#pragma unroll
    for (int v = 0; v < 16; ++v) ksr[v] += __shfl_xor(ksr[v], m);
  }
  if (lr == 0) {
#pragma unroll
    for (int rt = 0; rt < 4; ++rt)
#pragma unroll
      for (int i = 0; i < 4; ++i)
        ksum[(rowBase + rt * 16 + kg * 4 + i) * NCLS + cls] = ksr[rt * 4 + i];
  }
}

// ---------------- kernel 2: per-row log-softmax loss + last-block reduce ----------------
// 64 blocks x 256 threads; 4 lanes per row (each covers 16 classes).
__global__ __launch_bounds__(256) void kde_loss3(const float* __restrict__ ksum,
                                                 const int* __restrict__ target,
                                                 const float* __restrict__ wptr,
                                                 const float* __restrict__ bptr,
                                                 float* __restrict__ partial,
                                                 int* __restrict__ cnt,
                                                 float* __restrict__ out) {
  const int tid = threadIdx.x;
  const int row = blockIdx.x * 64 + (tid >> 2);
  const int q   = tid & 3;                       // class quarter
  const float w = wptr[0], b = bptr[0];
  const int label = target[row];
  const float inv64 = 1.0f / 64.0f, inv63 = 1.0f / 63.0f;
  const float4* kr = (const float4*)(ksum + row * NCLS + q * 16);

  float p[16];
#pragma unroll
  for (int j4 = 0; j4 < 4; ++j4) {
    const float4 kv = kr[j4];
    const float kvv[4] = {kv.x, kv.y, kv.z, kv.w};
#pragma unroll
    for (int j = 0; j < 4; ++j) {
      const int c = q * 16 + j4 * 4 + j;
      p[j4 * 4 + j] = w * kvv[j] * ((c == label) ? inv63 : inv64) + b;
    }
  }
  float pmax = -1e30f, plab = -1e30f;
#pragma unroll
  for (int j = 0; j < 16; ++j) {
    pmax = fmaxf(pmax, p[j]);
    plab = fmaxf(plab, (q * 16 + j == label) ? p[j] : -1e30f);
  }
  pmax = fmaxf(pmax, __shfl_xor(pmax, 1));
  pmax = fmaxf(pmax, __shfl_xor(pmax, 2));
  plab = fmaxf(plab, __shfl_xor(plab, 1));
  plab = fmaxf(plab, __shfl_xor(plab, 2));
  float se = 0.f;
#pragma unroll
  for (int j = 0; j < 16; ++j) se += __expf(p[j] - pmax);
  se += __shfl_xor(se, 1);
  se += __shfl_xor(se, 2);
  float loss = 0.25f * (pmax + __logf(se) - plab);   // identical on the 4 lanes

  // block reduce (sum of 16 rows per wave, 4 waves)
#pragma unroll
  for (int m = 1; m < 64; m <<= 1) loss += __shfl_xor(loss, m);
  __shared__ float wsum[4];
  __shared__ int isLast;
  if ((tid & 63) == 0) wsum[tid >> 6] = loss;
  __syncthreads();
  if (tid == 0) {
    const float s = wsum[0] + wsum[1] + wsum[2] + wsum[3];
    __hip_atomic_store(&partial[blockIdx.x], s, __ATOMIC_RELEASE, __HIP_MEMORY_SCOPE_AGENT);
    const int old = __hip_atomic_fetch_add(cnt, 1, __ATOMIC_ACQ_REL, __HIP_MEMORY_SCOPE_AGENT);
    isLast = (old == 63);
  }
  __syncthreads();
  if (isLast && tid < 64) {
    float v = __hip_atomic_load(&partial[tid], __ATOMIC_ACQUIRE, __HIP_MEMORY_SCOPE_AGENT);
#pragma unroll
    for (int m = 1; m < 64; m <<= 1) v += __shfl_xor(v, m);
    if (tid == 0) *out = v;
  }
}

// ================= fp32 fallback (ws too small): fused, 64 blocks =================
__device__ __forceinline__ void load_tile64(const float4* __restrict__ g, float4* lds) {
  const int t = threadIdx.x;
#pragma unroll
  for (int p = 0; p < 4; ++p) {
    const int ch  = t + p * 256;
    const int row = ch >> 4, k4 = ch & 15;
    lds[row * S4 + k4] = g[row * 16 + k4];
  }
}

__device__ __forceinline__ void sqnorm64(const float4* lds, float* sq) {
  const int t = threadIdx.x;
  if (t < 64) {
    float s = 0.f;
#pragma unroll
    for (int k4 = 0; k4 < 16; ++k4) {
      const float4 v = lds[t * S4 + k4];
      s += v.x * v.x + v.y * v.y + v.z * v.z + v.w * v.w;
    }
    sq[t] = s;
  }
}

__device__ __forceinline__ void tile_ksum(const float4* rowE, const float4* colE,
                                          const float* sqRow, const float* sqCol,
                                          int rowBase, int colBase, float inv2bw,
                                          float ks[4]) {
  const int t  = threadIdx.x;
  const int cq = t & 15, rq = t >> 4;
  float dot[4][4];
#pragma unroll
  for (int m = 0; m < 4; ++m)
#pragma unroll
    for (int n = 0; n < 4; ++n) dot[m][n] = 0.f;

#pragma unroll 4
  for (int k4 = 0; k4 < 16; ++k4) {
    float4 a[4], bb[4];
#pragma unroll
    for (int m = 0; m < 4; ++m) a[m] = rowE[(rq + 16 * m) * S4 + k4];
#pragma unroll
    for (int n = 0; n < 4; ++n) bb[n] = colE[(cq + 16 * n) * S4 + k4];
#pragma unroll
    for (int m = 0; m < 4; ++m)
#pragma unroll
      for (int n = 0; n < 4; ++n) {
        dot[m][n] += a[m].x * bb[n].x;
        dot[m][n] += a[m].y * bb[n].y;
        dot[m][n] += a[m].z * bb[n].z;
        dot[m][n] += a[m].w * bb[n].w;
      }
  }

#pragma unroll
  for (int m = 0; m < 4; ++m) {
    const int r  = rq + 16 * m;
    const int gr = rowBase + r;
    const float sr = sqRow[r];
    float s = 0.f;
#pragma unroll
    for (int n = 0; n < 4; ++n) {
      const int c  = cq + 16 * n;
      const int gc = colBase + c;
      float d2 = sr + sqCol[c] - 2.f * dot[m][n];
      d2 = fmaxf(d2, 0.f);
      const float K = __expf(-sqrtf(d2) * inv2bw);
      s += (gr != gc) ? K : 0.f;
    }
    s += __shfl_xor(s, 1);
    s += __shfl_xor(s, 2);
    s += __shfl_xor(s, 4);
    s += __shfl_xor(s, 8);
    ks[m] = s;
  }
}

__global__ __launch_bounds__(256) void kde_fused(const float* __restrict__ emb,
                                                 const float* __restrict__ bwv,
                                                 const int* __restrict__ target,
                                                 const float* __restrict__ wptr,
                                                 const float* __restrict__ bptr,
                                                 float* __restrict__ out) {
  __shared__ float4 rowE[64 * S4];
  __shared__ float4 colE[64 * S4];
  __shared__ float sqRow[64], sqCol[64];
  __shared__ float ksumL[64 * NCLS];

  const int rg = blockIdx.x;
  const int rowBase = rg * 64;

  load_tile64((const float4*)(emb + rowBase * EMB), rowE);
  __syncthreads();
  sqnorm64(rowE, sqRow);

  for (int cls = 0; cls < NCLS; ++cls) {
    const int colBase = cls * 64;
    __syncthreads();
    load_tile64((const float4*)(emb + colBase * EMB), colE);
    __syncthreads();
    sqnorm64(colE, sqCol);
    __syncthreads();

    const float inv2bw = 1.0f / (2.0f * bwv[cls]);
    float ks[4];
    tile_ksum(rowE, colE, sqRow, sqCol, rowBase, colBase, inv2bw, ks);
    if ((threadIdx.x & 15) == 0) {
      const int rq = threadIdx.x >> 4;
#pragma unroll
      for (int m = 0; m < 4; ++m)
        ksumL[(rq + 16 * m) * NCLS + cls] = ks[m];
    }
  }
  __syncthreads();

  float loss = 0.f;
  if (threadIdx.x < 64) {
    const int r = threadIdx.x;
    const int row = rowBase + r;
    const int label = target[row];
    const float w = wptr[0], b = bptr[0];
    const float inv64 = 1.0f / 64.0f, inv63 = 1.0f / 63.0f;
    float pmax = -1e30f, plabel = 0.f;
    for (int c = 0; c < NCLS; ++c) {
      const float p = w * ksumL[r * NCLS + c] * ((c == label) ? inv63 : inv64) + b;
      pmax = fmaxf(pmax, p);
      plabel = (c == label) ? p : plabel;
    }
    float se = 0.f;
    for (int c = 0; c < NCLS; ++c) {
      const float p = w * ksumL[r * NCLS + c] * ((c == label) ? inv63 : inv64) + b;
      se += __expf(p - pmax);
    }
    loss = pmax + __logf(se) - plabel;
  }

  __shared__ float red[256];
  red[threadIdx.x] = loss;
  __syncthreads();
  for (int s = 128; s > 0; s >>= 1) {
    if (threadIdx.x < s) red[threadIdx.x] += red[threadIdx.x + s];
    __syncthreads();
  }
  if (threadIdx.x == 0) atomicAdd(out, red[0]);
}

}  // namespace

extern "C" void kernel_launch(void* const* d_in, const int* in_sizes, int n_in,
                              void* d_out, int out_size, void* d_ws, size_t ws_size,
                              hipStream_t stream) {
  const float* emb    = (const float*)d_in[0];
  const float* bwv    = (const float*)d_in[1];
  const float* wptr   = (const float*)d_in[2];
  const float* bptr   = (const float*)d_in[3];
  const int*   target = (const int*)d_in[4];
  float* out = (float*)d_out;

  if (ws_size >= WS_NEED) {
    float* ksum    = (float*)((char*)d_ws + KS_OFF);
    float* partial = (float*)((char*)d_ws + PART_OFF);
    int*   cnt     = (int*)((char*)d_ws + CNT_OFF);

    kde_ksum_mfma<<<1024, 256, 0, stream>>>(emb, bwv, ksum, cnt);
    kde_loss3<<<64, 256, 0, stream>>>(ksum, target, wptr, bptr, partial, cnt, out);
  } else {
    hipMemsetAsync(out, 0, sizeof(float), stream);
    kde_fused<<<64, 256, 0, stream>>>(emb, bwv, target, wptr, bptr, out);
  }
}

// Round 13
// 27.875 us; speedup vs baseline: 1.0763x; 1.0763x over previous
//
#include <hip/hip_runtime.h>

namespace {

constexpr int EMB  = 64;
constexpr int NCLS = 64;
constexpr int BTOT = 4096;
constexpr int S4   = 17;   // float4 stride for fallback LDS tiles

typedef __bf16 bf16x8 __attribute__((ext_vector_type(8)));
typedef float  f32x4  __attribute__((ext_vector_type(4)));

// ---------------- ws layout ----------------
constexpr size_t EMBH_OFF = 0;                                   // 4096*64 bf16 = 512 KB
constexpr size_t SQ_OFF   = 524288;                              // 4096 f32 = 16 KB
constexpr size_t KS_OFF   = 540672;                              // 4096*64 f32 = 1 MB
constexpr size_t PART_OFF = KS_OFF + (size_t)BTOT * NCLS * 4;    // 64 f32 partials
constexpr size_t CNT_OFF  = PART_OFF + 64 * 4;                   // 1 int counter
constexpr size_t WS_NEED  = CNT_OFF + 16;

__device__ __forceinline__ ushort f2bf(float x) {     // RNE fp32 -> bf16
  uint u = __float_as_uint(x);
  uint r = (u + 0x7fffu + ((u >> 16) & 1u)) >> 16;
  return (ushort)r;
}

// ---------------- kernel 0: convert + sqnorm + counter reset ----------------
// 256 blocks x 256 threads; thread t handles float4 #t (row = t/16).
__global__ __launch_bounds__(256) void kde_prep(const float* __restrict__ emb,
                                                ushort* __restrict__ embh,
                                                float* __restrict__ sq,
                                                int* __restrict__ cnt) {
  if (blockIdx.x == 0 && threadIdx.x == 0) *cnt = 0;   // visible to kde_loss3 (later dispatch)

  const int t = blockIdx.x * 256 + threadIdx.x;        // 0..65535
  const float4 v = ((const float4*)emb)[t];
  ushort4 o;
  o.x = f2bf(v.x); o.y = f2bf(v.y); o.z = f2bf(v.z); o.w = f2bf(v.w);
  ((ushort4*)embh)[t] = o;

  float s = v.x * v.x + v.y * v.y + v.z * v.z + v.w * v.w;
  s += __shfl_xor(s, 1);
  s += __shfl_xor(s, 2);
  s += __shfl_xor(s, 4);
  s += __shfl_xor(s, 8);
  if ((threadIdx.x & 15) == 0) sq[t >> 4] = s;
}

// ---------------- kernel 1: Ksum via MFMA (R11 structure + exp2 fold) ----------------
// grid 1024 x 256: block -> (rg = bid>>4: 64 rows, cg = bid&15), wave w -> class cg*4+w.
// Wave: 4 row-tiles x 4 col-tiles, 2 MFMA (K=64) each; epilogue sqrt/exp + shfl reduce.
// Plain loads (compiler hoists; manual pipelining slower, R9). Fast raw v_sqrt_f32
// (R11: -2.0us). exp2f with log2(e) folded into the bandwidth constant (one fewer
// v_mul per element; validated absmax 0 in R8/R12).
__global__ __launch_bounds__(256, 4) void kde_ksum_mfma(const __bf16* __restrict__ embh,
                                                        const float* __restrict__ sq,
                                                        const float* __restrict__ bwv,
                                                        float* __restrict__ ksum) {
  const int tid  = threadIdx.x;
  const int wave = tid >> 6;
  const int lane = tid & 63;
  const int bid  = blockIdx.x;
  const int rowBase = (bid >> 4) * 64;
  const int cls  = (bid & 15) * 4 + wave;
  const int colBase = cls * 64;

  const int lr = lane & 15;   // A row / B col within 16
  const int kg = lane >> 4;   // k-group (8 elems each)
  const int koff = kg * 8;

  // A fragments: 4 row-tiles
  bf16x8 a0[4], a1[4];
#pragma unroll
  for (int rt = 0; rt < 4; ++rt) {
    const __bf16* ar = embh + (rowBase + rt * 16 + lr) * EMB;
    a0[rt] = *(const bf16x8*)(ar + koff);
    a1[rt] = *(const bf16x8*)(ar + 32 + koff);
  }

  // squared norms for this lane's 16 output rows (rt*16 + kg*4 + i)
  float srv[16];
#pragma unroll
  for (int rt = 0; rt < 4; ++rt) {
    const float4 s4 = *(const float4*)(sq + rowBase + rt * 16 + kg * 4);
    srv[rt * 4 + 0] = s4.x; srv[rt * 4 + 1] = s4.y;
    srv[rt * 4 + 2] = s4.z; srv[rt * 4 + 3] = s4.w;
  }

  constexpr float NLOG2E = -1.4426950408889634f;   // -log2(e)
  const float nl2bw = NLOG2E / (2.0f * bwv[cls]);

  float ksr[16];
#pragma unroll
  for (int v = 0; v < 16; ++v) ksr[v] = 0.f;

#pragma unroll
  for (int ct = 0; ct < 4; ++ct) {
    const int c0 = colBase + ct * 16;
    const __bf16* br = embh + (c0 + lr) * EMB;
    const bf16x8 b0 = *(const bf16x8*)(br + koff);
    const bf16x8 b1 = *(const bf16x8*)(br + 32 + koff);
    const int gc = c0 + lr;
    const float sc = sq[gc];
#pragma unroll
    for (int rt = 0; rt < 4; ++rt) {
      f32x4 acc = {0.f, 0.f, 0.f, 0.f};
      acc = __builtin_amdgcn_mfma_f32_16x16x32_bf16(a0[rt], b0, acc, 0, 0, 0);
      acc = __builtin_amdgcn_mfma_f32_16x16x32_bf16(a1[rt], b1, acc, 0, 0, 0);
      // D layout: col = lane&15 (= gc), row = kg*4 + i
#pragma unroll
      for (int i = 0; i < 4; ++i) {
        const int gr = rowBase + rt * 16 + kg * 4 + i;
        float d2 = fmaf(-2.f, acc[i], srv[rt * 4 + i] + sc);
        d2 = fmaxf(d2, 0.f);
        const float dist = __builtin_amdgcn_sqrtf(d2);   // raw v_sqrt_f32
        const float Kv = exp2f(dist * nl2bw);            // exp(-dist/(2bw))
        ksr[rt * 4 + i] += (gr != gc) ? Kv : 0.f;
      }
    }
  }

  // reduce over the 16 lanes (lr) that hold different cols
#pragma unroll
  for (int m = 1; m < 16; m <<= 1) {
#pragma unroll
    for (int v = 0; v < 16; ++v) ksr[v] += __shfl_xor(ksr[v], m);
  }
  if (lr == 0) {
#pragma unroll
    for (int rt = 0; rt < 4; ++rt)
#pragma unroll
      for (int i = 0; i < 4; ++i)
        ksum[(rowBase + rt * 16 + kg * 4 + i) * NCLS + cls] = ksr[rt * 4 + i];
  }
}

// ---------------- kernel 2: per-row log-softmax loss + last-block reduce ----------------
// 64 blocks x 256 threads; 4 lanes per row (each covers 16 classes).
__global__ __launch_bounds__(256) void kde_loss3(const float* __restrict__ ksum,
                                                 const int* __restrict__ target,
                                                 const float* __restrict__ wptr,
                                                 const float* __restrict__ bptr,
                                                 float* __restrict__ partial,
                                                 int* __restrict__ cnt,
                                                 float* __restrict__ out) {
  const int tid = threadIdx.x;
  const int row = blockIdx.x * 64 + (tid >> 2);
  const int q   = tid & 3;                       // class quarter
  const float w = wptr[0], b = bptr[0];
  const int label = target[row];
  const float inv64 = 1.0f / 64.0f, inv63 = 1.0f / 63.0f;
  const float4* kr = (const float4*)(ksum + row * NCLS + q * 16);

  float p[16];
#pragma unroll
  for (int j4 = 0; j4 < 4; ++j4) {
    const float4 kv = kr[j4];
    const float kvv[4] = {kv.x, kv.y, kv.z, kv.w};
#pragma unroll
    for (int j = 0; j < 4; ++j) {
      const int c = q * 16 + j4 * 4 + j;
      p[j4 * 4 + j] = w * kvv[j] * ((c == label) ? inv63 : inv64) + b;
    }
  }
  float pmax = -1e30f, plab = -1e30f;
#pragma unroll
  for (int j = 0; j < 16; ++j) {
    pmax = fmaxf(pmax, p[j]);
    plab = fmaxf(plab, (q * 16 + j == label) ? p[j] : -1e30f);
  }
  pmax = fmaxf(pmax, __shfl_xor(pmax, 1));
  pmax = fmaxf(pmax, __shfl_xor(pmax, 2));
  plab = fmaxf(plab, __shfl_xor(plab, 1));
  plab = fmaxf(plab, __shfl_xor(plab, 2));
  float se = 0.f;
#pragma unroll
  for (int j = 0; j < 16; ++j) se += __expf(p[j] - pmax);
  se += __shfl_xor(se, 1);
  se += __shfl_xor(se, 2);
  float loss = 0.25f * (pmax + __logf(se) - plab);   // identical on the 4 lanes

  // block reduce (sum of 16 rows per wave, 4 waves)
#pragma unroll
  for (int m = 1; m < 64; m <<= 1) loss += __shfl_xor(loss, m);
  __shared__ float wsum[4];
  __shared__ int isLast;
  if ((tid & 63) == 0) wsum[tid >> 6] = loss;
  __syncthreads();
  if (tid == 0) {
    const float s = wsum[0] + wsum[1] + wsum[2] + wsum[3];
    __hip_atomic_store(&partial[blockIdx.x], s, __ATOMIC_RELEASE, __HIP_MEMORY_SCOPE_AGENT);
    const int old = __hip_atomic_fetch_add(cnt, 1, __ATOMIC_ACQ_REL, __HIP_MEMORY_SCOPE_AGENT);
    isLast = (old == 63);
  }
  __syncthreads();
  if (isLast && tid < 64) {
    float v = __hip_atomic_load(&partial[tid], __ATOMIC_ACQUIRE, __HIP_MEMORY_SCOPE_AGENT);
#pragma unroll
    for (int m = 1; m < 64; m <<= 1) v += __shfl_xor(v, m);
    if (tid == 0) *out = v;
  }
}

// ================= fp32 fallback (ws too small): fused, 64 blocks =================
__device__ __forceinline__ void load_tile64(const float4* __restrict__ g, float4* lds) {
  const int t = threadIdx.x;
#pragma unroll
  for (int p = 0; p < 4; ++p) {
    const int ch  = t + p * 256;
    const int row = ch >> 4, k4 = ch & 15;
    lds[row * S4 + k4] = g[row * 16 + k4];
  }
}

__device__ __forceinline__ void sqnorm64(const float4* lds, float* sq) {
  const int t = threadIdx.x;
  if (t < 64) {
    float s = 0.f;
#pragma unroll
    for (int k4 = 0; k4 < 16; ++k4) {
      const float4 v = lds[t * S4 + k4];
      s += v.x * v.x + v.y * v.y + v.z * v.z + v.w * v.w;
    }
    sq[t] = s;
  }
}

__device__ __forceinline__ void tile_ksum(const float4* rowE, const float4* colE,
                                          const float* sqRow, const float* sqCol,
                                          int rowBase, int colBase, float inv2bw,
                                          float ks[4]) {
  const int t  = threadIdx.x;
  const int cq = t & 15, rq = t >> 4;
  float dot[4][4];
#pragma unroll
  for (int m = 0; m < 4; ++m)
#pragma unroll
    for (int n = 0; n < 4; ++n) dot[m][n] = 0.f;

#pragma unroll 4
  for (int k4 = 0; k4 < 16; ++k4) {
    float4 a[4], bb[4];
#pragma unroll
    for (int m = 0; m < 4; ++m) a[m] = rowE[(rq + 16 * m) * S4 + k4];
#pragma unroll
    for (int n = 0; n < 4; ++n) bb[n] = colE[(cq + 16 * n) * S4 + k4];
#pragma unroll
    for (int m = 0; m < 4; ++m)
#pragma unroll
      for (int n = 0; n < 4; ++n) {
        dot[m][n] += a[m].x * bb[n].x;
        dot[m][n] += a[m].y * bb[n].y;
        dot[m][n] += a[m].z * bb[n].z;
        dot[m][n] += a[m].w * bb[n].w;
      }
  }

#pragma unroll
  for (int m = 0; m < 4; ++m) {
    const int r  = rq + 16 * m;
    const int gr = rowBase + r;
    const float sr = sqRow[r];
    float s = 0.f;
#pragma unroll
    for (int n = 0; n < 4; ++n) {
      const int c  = cq + 16 * n;
      const int gc = colBase + c;
      float d2 = sr + sqCol[c] - 2.f * dot[m][n];
      d2 = fmaxf(d2, 0.f);
      const float K = __expf(-sqrtf(d2) * inv2bw);
      s += (gr != gc) ? K : 0.f;
    }
    s += __shfl_xor(s, 1);
    s += __shfl_xor(s, 2);
    s += __shfl_xor(s, 4);
    s += __shfl_xor(s, 8);
    ks[m] = s;
  }
}

__global__ __launch_bounds__(256) void kde_fused(const float* __restrict__ emb,
                                                 const float* __restrict__ bwv,
                                                 const int* __restrict__ target,
                                                 const float* __restrict__ wptr,
                                                 const float* __restrict__ bptr,
                                                 float* __restrict__ out) {
  __shared__ float4 rowE[64 * S4];
  __shared__ float4 colE[64 * S4];
  __shared__ float sqRow[64], sqCol[64];
  __shared__ float ksumL[64 * NCLS];

  const int rg = blockIdx.x;
  const int rowBase = rg * 64;

  load_tile64((const float4*)(emb + rowBase * EMB), rowE);
  __syncthreads();
  sqnorm64(rowE, sqRow);

  for (int cls = 0; cls < NCLS; ++cls) {
    const int colBase = cls * 64;
    __syncthreads();
    load_tile64((const float4*)(emb + colBase * EMB), colE);
    __syncthreads();
    sqnorm64(colE, sqCol);
    __syncthreads();

    const float inv2bw = 1.0f / (2.0f * bwv[cls]);
    float ks[4];
    tile_ksum(rowE, colE, sqRow, sqCol, rowBase, colBase, inv2bw, ks);
    if ((threadIdx.x & 15) == 0) {
      const int rq = threadIdx.x >> 4;
#pragma unroll
      for (int m = 0; m < 4; ++m)
        ksumL[(rq + 16 * m) * NCLS + cls] = ks[m];
    }
  }
  __syncthreads();

  float loss = 0.f;
  if (threadIdx.x < 64) {
    const int r = threadIdx.x;
    const int row = rowBase + r;
    const int label = target[row];
    const float w = wptr[0], b = bptr[0];
    const float inv64 = 1.0f / 64.0f, inv63 = 1.0f / 63.0f;
    float pmax = -1e30f, plabel = 0.f;
    for (int c = 0; c < NCLS; ++c) {
      const float p = w * ksumL[r * NCLS + c] * ((c == label) ? inv63 : inv64) + b;
      pmax = fmaxf(pmax, p);
      plabel = (c == label) ? p : plabel;
    }
    float se = 0.f;
    for (int c = 0; c < NCLS; ++c) {
      const float p = w * ksumL[r * NCLS + c] * ((c == label) ? inv63 : inv64) + b;
      se += __expf(p - pmax);
    }
    loss = pmax + __logf(se) - plabel;
  }

  __shared__ float red[256];
  red[threadIdx.x] = loss;
  __syncthreads();
  for (int s = 128; s > 0; s >>= 1) {
    if (threadIdx.x < s) red[threadIdx.x] += red[threadIdx.x + s];
    __syncthreads();
  }
  if (threadIdx.x == 0) atomicAdd(out, red[0]);
}

}  // namespace

extern "C" void kernel_launch(void* const* d_in, const int* in_sizes, int n_in,
                              void* d_out, int out_size, void* d_ws, size_t ws_size,
                              hipStream_t stream) {
  const float* emb    = (const float*)d_in[0];
  const float* bwv    = (const float*)d_in[1];
  const float* wptr   = (const float*)d_in[2];
  const float* bptr   = (const float*)d_in[3];
  const int*   target = (const int*)d_in[4];
  float* out = (float*)d_out;

  if (ws_size >= WS_NEED) {
    ushort* embh    = (ushort*)((char*)d_ws + EMBH_OFF);
    float*  sq      = (float*)((char*)d_ws + SQ_OFF);
    float*  ksum    = (float*)((char*)d_ws + KS_OFF);
    float*  partial = (float*)((char*)d_ws + PART_OFF);
    int*    cnt     = (int*)((char*)d_ws + CNT_OFF);

    kde_prep<<<256, 256, 0, stream>>>(emb, embh, sq, cnt);
    kde_ksum_mfma<<<1024, 256, 0, stream>>>((const __bf16*)embh, sq, bwv, ksum);
    kde_loss3<<<64, 256, 0, stream>>>(ksum, target, wptr, bptr, partial, cnt, out);
  } else {
    hipMemsetAsync(out, 0, sizeof(float), stream);
    kde_fused<<<64, 256, 0, stream>>>(emb, bwv, target, wptr, bptr, out);
  }
}